// Round 7
// baseline (271.918 us; speedup 1.0000x reference)
//
#include <hip/hip_runtime.h>

#define B_ 8
#define L_ 2048
#define CIN_ 256
#define COUT_ 256
#define HEADS_ 4
#define HD_ 64
#define NEG_SLOPE_ 0.2f
#define LOG2E_ 1.4426950408889634f

#define TI 32   // proj i-rows per block
#define TJ 64   // attn j-cols per tile
#define NJT (L_ / TJ)

typedef __attribute__((ext_vector_type(4))) float f32x4;
typedef __attribute__((ext_vector_type(8))) __bf16 bf16x8;
typedef __attribute__((ext_vector_type(4))) __bf16 bf16x4;

// MFMA 16x16x32 bf16 layouts (m89/m120-verified):
//  A[m][k]: m = lane&15, k = (lane>>4)*8 + e
//  B[k][n]: n = lane&15, k = (lane>>4)*8 + e
//  D[m][n]: n = lane&15, m = (lane>>4)*4 + reg
//
// hF ("B-frag-linear" h): for (b,h,jt,kt,nt) a 512-elem block, element
// (q*16+col)*8+e = h[channel h*64+nt*16+col][j = jt*64+kt*32+q*8+e].
// Rank-1 factorization: exp(leaky(a_i+d_j)) = max(E_i*F_j, E'_i*F'_j) — exact.
// abitsT transposed masks: abitsT[b][jw][row] (jw = j/64).
//
// R19 theory: attn was TRAFFIC-bound, not latency-bound (R13/R14/R18
// scheduling/occupancy edits all neutral). Old structure: 512 blocks x 1 MB
// hF re-read = 512 MB/iter ~ 81 µs at HBM — matches the ~75 µs residual.
// New attn: block = one (b,h) x 256 i-rows; per jt the 8 KB hF tile is
// staged ONCE into LDS (reg-staged, double-buffered, 1 barrier/jt) and
// shared by all 8 waves -> 64 MB global traffic (8x less). No j-half split,
// no combine buffer. Math/numerics identical.

// ---------------------------------------------------------------------------
// Kernel 0: pack adj int32 -> 1 bit, TRANSPOSED layout abitsT[b][jw][row].
// ---------------------------------------------------------------------------
__global__ __launch_bounds__(256, 4)
void pack_kernel(const int* __restrict__ adj, unsigned long long* __restrict__ abitsT) {
  const size_t wid = ((size_t)blockIdx.x * 256 + threadIdx.x) >> 6;  // 256-int chunk
  const int lane = threadIdx.x & 63;
  const int* p = adj + wid * 256 + lane;
  unsigned long long b0 = __ballot(p[0]   != 0);
  unsigned long long b1 = __ballot(p[64]  != 0);
  unsigned long long b2 = __ballot(p[128] != 0);
  unsigned long long b3 = __ballot(p[192] != 0);
  if (lane == 0) {
    const size_t row = wid >> 3;           // global row = b*2048 + i
    const int jw0 = (int)(wid & 7) * 4;    // first j-word of this chunk
    const size_t bb = row >> 11, l = row & 2047;
    unsigned long long* dst = abitsT + (bb << 16) + l;   // b*32*2048 + i
    dst[(size_t)(jw0 + 0) << 11] = b0;
    dst[(size_t)(jw0 + 1) << 11] = b1;
    dst[(size_t)(jw0 + 2) << 11] = b2;
    dst[(size_t)(jw0 + 3) << 11] = b3;
  }
}

// ---------------------------------------------------------------------------
// Kernel 1 (R18, unchanged): h = x@W^T via MFMA -> hF + (E,E')/(F,F').
// 512 thr = 8 waves; wave w8 = (head h, m-half mh). grid 512.
// ---------------------------------------------------------------------------
__global__ __launch_bounds__(512, 2)
void proj_kernel(const float* __restrict__ x, const float* __restrict__ W,
                 const float* __restrict__ att_src, const float* __restrict__ att_dst,
                 __bf16* __restrict__ hF, float2* __restrict__ aE,
                 float2* __restrict__ aF) {
  __shared__ __align__(16) __bf16 Wl[COUT_][72];
  __shared__ __align__(16) __bf16 Al[2][2][512];

  const int tid = threadIdx.x;
  const int r0 = blockIdx.x * TI;
  const int b  = r0 >> 11;
  const int l0 = r0 & (L_ - 1);

  const int w8 = tid >> 6, lane = tid & 63, col = lane & 15, q = lane >> 4;
  const int h  = w8 & 3;     // head
  const int mh = w8 >> 2;    // m-half (old mt)
  const int wrow = tid >> 3;          // [0,64): W row within 64-row group
  const int wc8  = (tid & 7) * 8;     // 8-col chunk
  const int si = tid >> 3, soct = tid & 7;   // Al staging (tid<256 only)

  f32x4 acc[4];
#pragma unroll
  for (int nt = 0; nt < 4; ++nt) acc[nt] = (f32x4)0.f;

  for (int kc = 0; kc < CIN_ / 64; ++kc) {
    __syncthreads();
#pragma unroll
    for (int rg = 0; rg < 4; ++rg) {
      const int row = rg * 64 + wrow;
      const float4* ws = (const float4*)(W + (size_t)row * CIN_ + kc * 64 + wc8);
#pragma unroll
      for (int u = 0; u < 2; ++u) {
        float4 f = ws[u];
        bf16x4 v;
        v[0] = (__bf16)f.x; v[1] = (__bf16)f.y; v[2] = (__bf16)f.z; v[3] = (__bf16)f.w;
        *(bf16x4*)&Wl[row][wc8 + u * 4] = v;
      }
    }
    if (tid < 256) {
      const float4* xs = (const float4*)(x + (size_t)(r0 + si) * CIN_ + kc * 64 + soct * 8);
      float4 f0 = xs[0], f1 = xs[1];
      bf16x8 v;
      v[0] = (__bf16)f0.x; v[1] = (__bf16)f0.y; v[2] = (__bf16)f0.z; v[3] = (__bf16)f0.w;
      v[4] = (__bf16)f1.x; v[5] = (__bf16)f1.y; v[6] = (__bf16)f1.z; v[7] = (__bf16)f1.w;
      *(bf16x8*)&Al[si >> 4][soct >> 2][(((soct & 3) << 4) + (si & 15)) << 3] = v;
    }
    __syncthreads();

    bf16x8 af[2], bfr[2][4];
#pragma unroll
    for (int kt = 0; kt < 2; ++kt)
      af[kt] = *(const bf16x8*)&Al[mh][kt][lane << 3];
#pragma unroll
    for (int kt = 0; kt < 2; ++kt)
#pragma unroll
      for (int nt = 0; nt < 4; ++nt)
        bfr[kt][nt] = *(const bf16x8*)&Wl[h * 64 + nt * 16 + col][kt * 32 + q * 8];
#pragma unroll
    for (int kt = 0; kt < 2; ++kt)
#pragma unroll
      for (int nt = 0; nt < 4; ++nt)
        acc[nt] = __builtin_amdgcn_mfma_f32_16x16x32_bf16(
            af[kt], bfr[kt][nt], acc[nt], 0, 0, 0);
  }

  // ---- fused score factors (this wave's 16 rows) ----
  float asv[4], adv[4];
#pragma unroll
  for (int nt = 0; nt < 4; ++nt) {
    asv[nt] = att_src[h * 64 + nt * 16 + col];
    adv[nt] = att_dst[h * 64 + nt * 16 + col];
  }
#pragma unroll
  for (int reg = 0; reg < 4; ++reg) {
    float s = 0.f, d = 0.f;
#pragma unroll
    for (int nt = 0; nt < 4; ++nt) {
      s = fmaf(acc[nt][reg], asv[nt], s);
      d = fmaf(acc[nt][reg], adv[nt], d);
    }
    s += __shfl_xor(s, 1, 64); d += __shfl_xor(d, 1, 64);
    s += __shfl_xor(s, 2, 64); d += __shfl_xor(d, 2, 64);
    s += __shfl_xor(s, 4, 64); d += __shfl_xor(d, 4, 64);
    s += __shfl_xor(s, 8, 64); d += __shfl_xor(d, 8, 64);
    if (col == 0) {
      const int il = mh * 16 + q * 4 + reg;
      const size_t idx = ((size_t)(b * HEADS_ + h) << 11) + l0 + il;
      float2 ev, fv;
      ev.x = __builtin_exp2f(s * LOG2E_);
      ev.y = __builtin_exp2f(s * (LOG2E_ * NEG_SLOPE_));
      fv.x = __builtin_exp2f(d * LOG2E_);
      fv.y = __builtin_exp2f(d * (LOG2E_ * NEG_SLOPE_));
      aE[idx] = ev;
      aF[idx] = fv;
    }
  }

  // ---- hF write: D-frag -> B-frag-linear ----
  {
    const int jt_p = l0 >> 6;
    const int kt_p = (l0 >> 5) & 1;
    const int qhi = q >> 1, qlo = q & 1;
    const int qp = mh * 2 + qhi;
#pragma unroll
    for (int nt = 0; nt < 4; ++nt) {
      bf16x4 v;
      v[0] = (__bf16)acc[nt][0];
      v[1] = (__bf16)acc[nt][1];
      v[2] = (__bf16)acc[nt][2];
      v[3] = (__bf16)acc[nt][3];
      const size_t off =
          ((((size_t)(b * HEADS_ + h) * 32 + jt_p) * 2 + kt_p) * 4 + nt) * 512 +
          (qp * 16 + col) * 8 + qlo * 4;
      *(bf16x4*)(hF + off) = v;
    }
  }
}

// ---------------------------------------------------------------------------
// Kernel 2 (R19): block = one (b,h) x 256 i-rows, 8 waves x 32 rows, full-j
// per wave. Per jt: 8 KB hF tile reg-staged into LDS once (double-buffered,
// T14 issue-early/write-late, 1 barrier/jt), consumed by all 8 waves.
// Global hF traffic 512 MB -> 64 MB. No combine; lsum spans full j.
// ---------------------------------------------------------------------------
__global__ __launch_bounds__(512)
void attn_kernel(const __bf16* __restrict__ hF, const float2* __restrict__ aE,
                 const float2* __restrict__ aF,
                 const unsigned long long* __restrict__ abitsT,
                 float* __restrict__ out) {
  __shared__ __align__(16) __bf16 kv[2][4096];   // 16 KB double-buffered hF tile

  const int tid = threadIdx.x;
  const int b  = blockIdx.x & 7;            // XCD spread
  const int hh = (blockIdx.x >> 3) & 3;     // head
  const int ib = blockIdx.x >> 5;           // i-block (0..7), 256 rows each

  const int w = tid >> 6, lane = tid & 63, col = lane & 15, q = lane >> 4;
  const int iw0 = ib * 256 + w * 32;        // wave's first i-row within batch

  const size_t hl = (size_t)(b * HEADS_ + hh);
  const float2 EE[2] = {aE[(hl << 11) + iw0 + col],
                        aE[(hl << 11) + iw0 + 16 + col]};
  const float* afb = (const float*)(aF + (hl << 11)) + q * 16;
  const __bf16* hbase = hF + hl * 131072;
  const unsigned long long* mb = abitsT + ((size_t)b << 16) + iw0 + col;

  f32x4 acc[2][4];
  float lsum[2] = {0.f, 0.f};   // per-lane partial sum_j P for row=col
#pragma unroll
  for (int mt = 0; mt < 2; ++mt)
#pragma unroll
    for (int nt = 0; nt < 4; ++nt) acc[mt][nt] = (f32x4)0.f;

  // prologue: stage jt=0 tile
  {
    float4 r0 = *(const float4*)(hbase + tid * 8);
    *(float4*)((char*)&kv[0][0] + tid * 16) = r0;
  }
  __syncthreads();

  int cur = 0;
  for (int jt = 0; jt < NJT; ++jt) {
    // issue next tile's global load early (T14); consumed after the barrier
    float4 rnext;
    if (jt < NJT - 1)
      rnext = *(const float4*)(hbase + (size_t)(jt + 1) * 4096 + tid * 8);

    const unsigned long long cm0 = mb[(size_t)jt << 11];
    const unsigned long long cm1 = mb[((size_t)jt << 11) + 16];

#pragma unroll
    for (int kt = 0; kt < 2; ++kt) {
      bf16x8 cb0 = *(const bf16x8*)&kv[cur][(kt * 4 + 0) * 512 + lane * 8];
      bf16x8 cb1 = *(const bf16x8*)&kv[cur][(kt * 4 + 1) * 512 + lane * 8];
      bf16x8 cb2 = *(const bf16x8*)&kv[cur][(kt * 4 + 2) * 512 + lane * 8];
      bf16x8 cb3 = *(const bf16x8*)&kv[cur][(kt * 4 + 3) * 512 + lane * 8];
      float cf[16];
#pragma unroll
      for (int u = 0; u < 4; ++u)
        *(float4*)&cf[u * 4] =
            *(const float4*)(afb + jt * 128 + kt * 64 + u * 4);

      bf16x8 av[2];
#pragma unroll
      for (int mt = 0; mt < 2; ++mt) {
        const unsigned long long bw = mt ? cm1 : cm0;
        const unsigned int tsh = ((unsigned int)(bw >> (kt * 32))) >> (q * 8);
        const float Ex = EE[mt].x, Ey = EE[mt].y;
        float part = 0.f;
#pragma unroll
        for (int e = 0; e < 8; ++e) {
          const float m1 = Ex * cf[2 * e];
          const float m2 = Ey * cf[2 * e + 1];
          const float pm = fmaxf(m1, m2);
          const float p = (tsh & (1u << e)) ? pm : 0.f;
          part += p;
          av[mt][e] = (__bf16)p;
        }
        lsum[mt] += part;
      }
#pragma unroll
      for (int mt = 0; mt < 2; ++mt) {
        acc[mt][0] = __builtin_amdgcn_mfma_f32_16x16x32_bf16(av[mt], cb0, acc[mt][0], 0, 0, 0);
        acc[mt][1] = __builtin_amdgcn_mfma_f32_16x16x32_bf16(av[mt], cb1, acc[mt][1], 0, 0, 0);
        acc[mt][2] = __builtin_amdgcn_mfma_f32_16x16x32_bf16(av[mt], cb2, acc[mt][2], 0, 0, 0);
        acc[mt][3] = __builtin_amdgcn_mfma_f32_16x16x32_bf16(av[mt], cb3, acc[mt][3], 0, 0, 0);
      }
    }

    // write-late: land next tile in the other buffer, one barrier per jt
    if (jt < NJT - 1)
      *(float4*)((char*)&kv[cur ^ 1][0] + tid * 16) = rnext;
    __syncthreads();
    cur ^= 1;
  }

  // complete lsum across q-groups: lane then holds sum_j P(row=col, half mt)
#pragma unroll
  for (int mt = 0; mt < 2; ++mt) {
    lsum[mt] += __shfl_xor(lsum[mt], 16, 64);
    lsum[mt] += __shfl_xor(lsum[mt], 32, 64);
  }

  // ---- epilogue: normalize and store (no combine needed) ----
#pragma unroll
  for (int mt = 0; mt < 2; ++mt) {
#pragma unroll
    for (int reg = 0; reg < 4; ++reg) {
      const int m = q * 4 + reg;
      // denominator for row m lives in lanes whose col == m
      const float lm = __shfl(lsum[mt], m, 64);
      const float linv = 1.0f / lm;
      const size_t orow =
          ((size_t)(b * L_ + iw0 + mt * 16 + m)) * COUT_ + hh * 64;
#pragma unroll
      for (int nt = 0; nt < 4; ++nt)
        out[orow + nt * 16 + col] = acc[mt][nt][reg] * linv;
    }
  }
}

// ---------------------------------------------------------------------------
extern "C" void kernel_launch(void* const* d_in, const int* in_sizes, int n_in,
                              void* d_out, int out_size, void* d_ws, size_t ws_size,
                              hipStream_t stream) {
  const float* x       = (const float*)d_in[0];
  const int*   adj     = (const int*)d_in[1];
  const float* W       = (const float*)d_in[2];
  const float* att_src = (const float*)d_in[3];
  const float* att_dst = (const float*)d_in[4];
  float* out = (float*)d_out;

  char* ws = (char*)d_ws;
  __bf16* hF = (__bf16*)ws;                                   // 8 MB frag-linear
  float2* aE = (float2*)(ws + (8u << 20));                    // 512 KB (E,E')
  float2* aF = (float2*)(ws + (9u << 20));                    // 512 KB (F,F')
  unsigned long long* abitsT =
      (unsigned long long*)(ws + (10u << 20));                // 4 MB transposed

  pack_kernel<<<(B_ * L_ * (L_ / 256)) / 4, 256, 0, stream>>>(adj, abitsT);
  proj_kernel<<<(B_ * L_) / TI, 512, 0, stream>>>(x, W, att_src, att_dst, hF, aE, aF);
  attn_kernel<<<B_ * HEADS_ * (L_ / 256), 512, 0, stream>>>(hF, aE, aF, abitsT, out);
}

// Round 8
// 261.957 us; speedup vs baseline: 1.0380x; 1.0380x over previous
//
#include <hip/hip_runtime.h>

#define B_ 8
#define L_ 2048
#define CIN_ 256
#define COUT_ 256
#define HEADS_ 4
#define HD_ 64
#define NEG_SLOPE_ 0.2f
#define LOG2E_ 1.4426950408889634f

#define TI 32   // proj i-rows per block
#define TJ 64   // attn j-cols per tile
#define NJT (L_ / TJ)

typedef __attribute__((ext_vector_type(4))) float f32x4;
typedef __attribute__((ext_vector_type(8))) __bf16 bf16x8;
typedef __attribute__((ext_vector_type(4))) __bf16 bf16x4;

// MFMA 16x16x32 bf16 layouts (m89/m120-verified):
//  A[m][k]: m = lane&15, k = (lane>>4)*8 + e
//  B[k][n]: n = lane&15, k = (lane>>4)*8 + e
//  D[m][n]: n = lane&15, m = (lane>>4)*4 + reg
//
// hF ("B-frag-linear" h): for (b,h,jt,kt,nt) a 512-elem block, element
// (q*16+col)*8+e = h[channel h*64+nt*16+col][j = jt*64+kt*32+q*8+e].
// Rank-1 factorization: exp(leaky(a_i+d_j)) = max(E_i*F_j, E'_i*F'_j) — exact.
// abitsT transposed masks: abitsT[b][jw][row] (jw = j/64).
//
// R20: dispatch-count reduction — pack FOLDED INTO proj's 512 blocks
// (R16-done-right: R16 failed because 32768 pack-only blocks carried proj's
// 45 KB LDS -> 27% occupancy; here pack work rides on the SAME 512 blocks,
// zero occupancy change). Each block packs the 32 adj rows it projects,
// 1 row per wave per kc iteration: loads issued before the staging barriers,
// ballots+stores after the MFMA section -> the 134 MB adj stream overlaps
// the MFMA/LDS pipes. 3 dispatches -> 2. attn = R12 verbatim (best-measured).

// ---------------------------------------------------------------------------
// Kernel 1 (R20): proj + fused pack. 512 thr = 8 waves; wave w8 = (head h,
// m-half mh) for proj; wave w8 packs rows l0+w8*4 .. +3 (one per kc iter).
// ---------------------------------------------------------------------------
__global__ __launch_bounds__(512, 2)
void proj_kernel(const float* __restrict__ x, const float* __restrict__ W,
                 const float* __restrict__ att_src, const float* __restrict__ att_dst,
                 const int* __restrict__ adj, unsigned long long* __restrict__ abitsT,
                 __bf16* __restrict__ hF, float2* __restrict__ aE,
                 float2* __restrict__ aF) {
  __shared__ __align__(16) __bf16 Wl[COUT_][72];
  __shared__ __align__(16) __bf16 Al[2][2][512];

  const int tid = threadIdx.x;
  const int r0 = blockIdx.x * TI;
  const int b  = r0 >> 11;
  const int l0 = r0 & (L_ - 1);

  const int w8 = tid >> 6, lane = tid & 63, col = lane & 15, q = lane >> 4;
  const int h  = w8 & 3;     // head
  const int mh = w8 >> 2;    // m-half
  const int wrow = tid >> 3;          // [0,64): W row within 64-row group
  const int wc8  = (tid & 7) * 8;     // 8-col chunk
  const int si = tid >> 3, soct = tid & 7;   // Al staging (tid<256 only)

  f32x4 acc[4];
#pragma unroll
  for (int nt = 0; nt < 4; ++nt) acc[nt] = (f32x4)0.f;

  for (int kc = 0; kc < CIN_ / 64; ++kc) {
    // ---- fused pack, phase 1: issue this iteration's adj row loads early.
    // wave w8 packs row l0 + w8*4 + kc; 32 independent dword loads/lane land
    // under the staging + MFMA work below.
    const int prow = l0 + w8 * 4 + kc;
    const int* ap = adj + (((size_t)(b * L_ + prow)) << 11) + lane;
    int pv[32];
#pragma unroll
    for (int c = 0; c < 32; ++c) pv[c] = ap[c * 64];

    __syncthreads();
#pragma unroll
    for (int rg = 0; rg < 4; ++rg) {
      const int row = rg * 64 + wrow;
      const float4* ws = (const float4*)(W + (size_t)row * CIN_ + kc * 64 + wc8);
#pragma unroll
      for (int u = 0; u < 2; ++u) {
        float4 f = ws[u];
        bf16x4 v;
        v[0] = (__bf16)f.x; v[1] = (__bf16)f.y; v[2] = (__bf16)f.z; v[3] = (__bf16)f.w;
        *(bf16x4*)&Wl[row][wc8 + u * 4] = v;
      }
    }
    if (tid < 256) {
      const float4* xs = (const float4*)(x + (size_t)(r0 + si) * CIN_ + kc * 64 + soct * 8);
      float4 f0 = xs[0], f1 = xs[1];
      bf16x8 v;
      v[0] = (__bf16)f0.x; v[1] = (__bf16)f0.y; v[2] = (__bf16)f0.z; v[3] = (__bf16)f0.w;
      v[4] = (__bf16)f1.x; v[5] = (__bf16)f1.y; v[6] = (__bf16)f1.z; v[7] = (__bf16)f1.w;
      *(bf16x8*)&Al[si >> 4][soct >> 2][(((soct & 3) << 4) + (si & 15)) << 3] = v;
    }
    __syncthreads();

    bf16x8 af[2], bfr[2][4];
#pragma unroll
    for (int kt = 0; kt < 2; ++kt)
      af[kt] = *(const bf16x8*)&Al[mh][kt][lane << 3];
#pragma unroll
    for (int kt = 0; kt < 2; ++kt)
#pragma unroll
      for (int nt = 0; nt < 4; ++nt)
        bfr[kt][nt] = *(const bf16x8*)&Wl[h * 64 + nt * 16 + col][kt * 32 + q * 8];
#pragma unroll
    for (int kt = 0; kt < 2; ++kt)
#pragma unroll
      for (int nt = 0; nt < 4; ++nt)
        acc[nt] = __builtin_amdgcn_mfma_f32_16x16x32_bf16(
            af[kt], bfr[kt][nt], acc[nt], 0, 0, 0);

    // ---- fused pack, phase 2: ballots + one 8B store per word.
#pragma unroll
    for (int c = 0; c < 32; ++c) {
      const unsigned long long m = __ballot(pv[c] != 0);
      if (lane == 0)
        abitsT[((size_t)b << 16) + ((size_t)c << 11) + prow] = m;
    }
  }

  // ---- fused score factors (this wave's 16 rows) ----
  float asv[4], adv[4];
#pragma unroll
  for (int nt = 0; nt < 4; ++nt) {
    asv[nt] = att_src[h * 64 + nt * 16 + col];
    adv[nt] = att_dst[h * 64 + nt * 16 + col];
  }
#pragma unroll
  for (int reg = 0; reg < 4; ++reg) {
    float s = 0.f, d = 0.f;
#pragma unroll
    for (int nt = 0; nt < 4; ++nt) {
      s = fmaf(acc[nt][reg], asv[nt], s);
      d = fmaf(acc[nt][reg], adv[nt], d);
    }
    s += __shfl_xor(s, 1, 64); d += __shfl_xor(d, 1, 64);
    s += __shfl_xor(s, 2, 64); d += __shfl_xor(d, 2, 64);
    s += __shfl_xor(s, 4, 64); d += __shfl_xor(d, 4, 64);
    s += __shfl_xor(s, 8, 64); d += __shfl_xor(d, 8, 64);
    if (col == 0) {
      const int il = mh * 16 + q * 4 + reg;
      const size_t idx = ((size_t)(b * HEADS_ + h) << 11) + l0 + il;
      float2 ev, fv;
      ev.x = __builtin_exp2f(s * LOG2E_);
      ev.y = __builtin_exp2f(s * (LOG2E_ * NEG_SLOPE_));
      fv.x = __builtin_exp2f(d * LOG2E_);
      fv.y = __builtin_exp2f(d * (LOG2E_ * NEG_SLOPE_));
      aE[idx] = ev;
      aF[idx] = fv;
    }
  }

  // ---- hF write: D-frag -> B-frag-linear ----
  {
    const int jt_p = l0 >> 6;
    const int kt_p = (l0 >> 5) & 1;
    const int qhi = q >> 1, qlo = q & 1;
    const int qp = mh * 2 + qhi;
#pragma unroll
    for (int nt = 0; nt < 4; ++nt) {
      bf16x4 v;
      v[0] = (__bf16)acc[nt][0];
      v[1] = (__bf16)acc[nt][1];
      v[2] = (__bf16)acc[nt][2];
      v[3] = (__bf16)acc[nt][3];
      const size_t off =
          ((((size_t)(b * HEADS_ + h) * 32 + jt_p) * 2 + kt_p) * 4 + nt) * 512 +
          (qp * 16 + col) * 8 + qlo * 4;
      *(bf16x4*)(hF + off) = v;
    }
  }
}

// ---------------------------------------------------------------------------
// Kernel 2 (R12 verbatim — measured-best attn structure): split-j attention,
// no launch-bounds VGPR cap. 512 thr = 8 waves = 4 heads x 2 j-halves;
// partial (O,l) combined via LDS + one barrier.
// ---------------------------------------------------------------------------
__global__ __launch_bounds__(512)
void attn_kernel(const __bf16* __restrict__ hF, const float2* __restrict__ aE,
                 const float2* __restrict__ aF,
                 const unsigned long long* __restrict__ abitsT,
                 float* __restrict__ out) {
  __shared__ __align__(16) float comb[HEADS_][64][40];   // 40 KB combine buf

  const int tid = threadIdx.x;
  const int b  = blockIdx.x & 7;           // XCD swizzle
  const int i0 = (blockIdx.x >> 3) * 32;

  const int w = tid >> 6, lane = tid & 63, col = lane & 15, q = lane >> 4;
  const int hh = w & 3;                    // head
  const int jh = w >> 2;                   // j-half
  const int jt0 = jh * (NJT / 2), jt1 = jt0 + NJT / 2;

  const size_t hl = (size_t)(b * HEADS_ + hh);
  const float2 EE[2] = {aE[(hl << 11) + i0 + col],
                        aE[(hl << 11) + i0 + 16 + col]};
  const float* afb = (const float*)(aF + (hl << 11)) + q * 16;
  const __bf16* hb = hF + hl * 131072 + lane * 8;
  const unsigned long long* mb = abitsT + ((size_t)b << 16) + i0 + col;

  bf16x8 bones;
#pragma unroll
  for (int e = 0; e < 8; ++e) bones[e] = (__bf16)1.0f;

  f32x4 acc[2][4], accl[2];
#pragma unroll
  for (int mt = 0; mt < 2; ++mt) {
    accl[mt] = (f32x4)0.f;
#pragma unroll
    for (int nt = 0; nt < 4; ++nt) acc[mt][nt] = (f32x4)0.f;
  }

  unsigned long long cm0 = mb[(size_t)jt0 << 11];
  unsigned long long cm1 = mb[((size_t)jt0 << 11) + 16];

  for (int jt = jt0; jt < jt1; ++jt) {
    const int jn = (jt < jt1 - 1) ? jt + 1 : jt;
    const unsigned long long nm0 = mb[(size_t)jn << 11];
    const unsigned long long nm1 = mb[((size_t)jn << 11) + 16];

    // per-kt: load 4 cb frags + 4 cf float4s, build av for both mt, 10 MFMAs.
#pragma unroll
    for (int kt = 0; kt < 2; ++kt) {
      bf16x8 cb0 = *(const bf16x8*)(hb + jt * 4096 + (kt * 4 + 0) * 512);
      bf16x8 cb1 = *(const bf16x8*)(hb + jt * 4096 + (kt * 4 + 1) * 512);
      bf16x8 cb2 = *(const bf16x8*)(hb + jt * 4096 + (kt * 4 + 2) * 512);
      bf16x8 cb3 = *(const bf16x8*)(hb + jt * 4096 + (kt * 4 + 3) * 512);
      float cf[16];
#pragma unroll
      for (int u = 0; u < 4; ++u)
        *(float4*)&cf[u * 4] =
            *(const float4*)(afb + jt * 128 + kt * 64 + u * 4);

      bf16x8 av[2];
#pragma unroll
      for (int mt = 0; mt < 2; ++mt) {
        const unsigned long long bw = mt ? cm1 : cm0;
        const unsigned int tsh = ((unsigned int)(bw >> (kt * 32))) >> (q * 8);
        const float Ex = EE[mt].x, Ey = EE[mt].y;
#pragma unroll
        for (int e = 0; e < 8; ++e) {
          const float m1 = Ex * cf[2 * e];
          const float m2 = Ey * cf[2 * e + 1];
          const float pm = fmaxf(m1, m2);
          const float p = (tsh & (1u << e)) ? pm : 0.f;
          av[mt][e] = (__bf16)p;
        }
      }
#pragma unroll
      for (int mt = 0; mt < 2; ++mt) {
        acc[mt][0] = __builtin_amdgcn_mfma_f32_16x16x32_bf16(av[mt], cb0, acc[mt][0], 0, 0, 0);
        acc[mt][1] = __builtin_amdgcn_mfma_f32_16x16x32_bf16(av[mt], cb1, acc[mt][1], 0, 0, 0);
        acc[mt][2] = __builtin_amdgcn_mfma_f32_16x16x32_bf16(av[mt], cb2, acc[mt][2], 0, 0, 0);
        acc[mt][3] = __builtin_amdgcn_mfma_f32_16x16x32_bf16(av[mt], cb3, acc[mt][3], 0, 0, 0);
        accl[mt] = __builtin_amdgcn_mfma_f32_16x16x32_bf16(av[mt], bones, accl[mt], 0, 0, 0);
      }
    }

    cm0 = nm0; cm1 = nm1;
  }

  // ---- combine j-halves via LDS ----
  if (jh == 1) {
#pragma unroll
    for (int mt = 0; mt < 2; ++mt)
#pragma unroll
      for (int nt = 0; nt < 4; ++nt)
        *(f32x4*)&comb[hh][lane][mt * 16 + nt * 4] = acc[mt][nt];
    *(f32x4*)&comb[hh][lane][32] = accl[0];
    *(f32x4*)&comb[hh][lane][36] = accl[1];
  }
  __syncthreads();
  if (jh == 0) {
#pragma unroll
    for (int mt = 0; mt < 2; ++mt) {
      const f32x4 lo = accl[mt] + *(const f32x4*)&comb[hh][lane][32 + mt * 4];
#pragma unroll
      for (int reg = 0; reg < 4; ++reg) {
        const int m = q * 4 + reg;
        const float linv = 1.0f / lo[reg];
        const size_t orow =
            ((size_t)(b * L_ + i0 + mt * 16 + m)) * COUT_ + hh * 64;
#pragma unroll
        for (int nt = 0; nt < 4; ++nt) {
          const float v =
              acc[mt][nt][reg] + comb[hh][lane][mt * 16 + nt * 4 + reg];
          out[orow + nt * 16 + col] = v * linv;
        }
      }
    }
  }
}

// ---------------------------------------------------------------------------
extern "C" void kernel_launch(void* const* d_in, const int* in_sizes, int n_in,
                              void* d_out, int out_size, void* d_ws, size_t ws_size,
                              hipStream_t stream) {
  const float* x       = (const float*)d_in[0];
  const int*   adj     = (const int*)d_in[1];
  const float* W       = (const float*)d_in[2];
  const float* att_src = (const float*)d_in[3];
  const float* att_dst = (const float*)d_in[4];
  float* out = (float*)d_out;

  char* ws = (char*)d_ws;
  __bf16* hF = (__bf16*)ws;                                   // 8 MB frag-linear
  float2* aE = (float2*)(ws + (8u << 20));                    // 512 KB (E,E')
  float2* aF = (float2*)(ws + (9u << 20));                    // 512 KB (F,F')
  unsigned long long* abitsT =
      (unsigned long long*)(ws + (10u << 20));                // 4 MB transposed

  proj_kernel<<<(B_ * L_) / TI, 512, 0, stream>>>(
      x, W, att_src, att_dst, adj, abitsT, hF, aE, aF);
  attn_kernel<<<B_ * (L_ / 32), 512, 0, stream>>>(hF, aE, aF, abitsT, out);
}